// Round 8
// baseline (311.377 us; speedup 1.0000x reference)
//
#include <hip/hip_runtime.h>
#include <hip/hip_bf16.h>

// Simple_6270652252303. Inputs float32 (detector-verified; bf16 path kept as
// insurance). Text branch only feeds output.
//   k_A:    text -> LN -> LN -> t2(global) + ddx{de,de*x}; also computes the
//           collapsed head matrix M = cW1@cW2 (+k) on block0/wave0.
//   k_B:    BC GEMM: t2 @ [sW2|sW3] + bias -> BC {B,C} interleaved. 2 rows/wave.
//   k_scan: S6 scan (R7 chunked-parallel reduction) -> y (aliases t2 buffer).
//   k_head: out[row] = y[row] @ M + k  (thread per row; head collapsed).

typedef __hip_bfloat16 bf16;

#define BATCH 64
#define SEQ   63
#define ROWS  (BATCH * SEQ)   // 4032
#define DIN   100
#define H1    128
#define DM    100
#define NS    300

__device__ __forceinline__ float2 up2(unsigned u) {
    float2 r;
    r.x = __uint_as_float(u << 16);
    r.y = __uint_as_float(u & 0xffff0000u);
    return r;
}
template<bool ISB>
__device__ __forceinline__ float LD(const void* p, int i) {
    if (ISB) return __bfloat162float(((const bf16*)p)[i]);
    else     return ((const float*)p)[i];
}
template<bool ISB>
__device__ __forceinline__ float2 LD2(const void* p, int i) {   // elements 2i,2i+1
    if (ISB) return up2(((const unsigned*)p)[i]);
    else     return ((const float2*)p)[i];
}
// four independent reduction chains interleaved (latencies overlap)
__device__ __forceinline__ float4 waveReduceSum4(float4 v) {
#pragma unroll
    for (int off = 32; off > 0; off >>= 1) {
        const float a = __shfl_xor(v.x, off, 64);
        const float b = __shfl_xor(v.y, off, 64);
        const float c = __shfl_xor(v.z, off, 64);
        const float d = __shfl_xor(v.w, off, 64);
        v.x += a; v.y += b; v.z += c; v.w += d;
    }
    return v;
}
__device__ __forceinline__ float lrelu(float x) { return x >= 0.f ? x : 0.01f * x; }
__device__ __forceinline__ float softplusf(float x) {
    return (x > 20.f) ? x : log1pf(__expf(x));
}

// bf16-vs-f32 storage detector (wave-uniform ballot; no LDS, no barrier).
__device__ __forceinline__ bool detect_bf16(const unsigned short* __restrict__ probe) {
    const int l = threadIdx.x & 63;
    const unsigned u0 = probe[l * 2];
    const unsigned u1 = probe[l * 2 + 1];
    const float v0 = fabsf(__uint_as_float(u0 << 16));
    const float v1 = fabsf(__uint_as_float(u1 << 16));
    const bool big = !(v0 < 1000.f) || !(v1 < 1000.f);
    const bool zero_even = (u0 == 0u);
    const unsigned long long mb = __ballot(big);
    const unsigned long long mz = __ballot(zero_even);
    return (mb == 0ULL) && (__popcll(mz) < 32);
}

// ---------------------------------------------------------------------------
// k_A: serial row pipeline. 2 rows/wave, 4 waves/block, grid 504.
// LDS transposed [k][2 rows] -> per-k access is one broadcast b64.
// ---------------------------------------------------------------------------
template<bool ISB>
__device__ __forceinline__ void a_impl(
    const void* __restrict__ text,
    const void* __restrict__ tW1, const void* __restrict__ tb1,
    const void* __restrict__ tg1, const void* __restrict__ tbe1,
    const void* __restrict__ tW2, const void* __restrict__ tb2,
    const void* __restrict__ tg2, const void* __restrict__ tbe2,
    const void* __restrict__ sW1, const void* __restrict__ sb1,
    const void* __restrict__ cW1, const void* __restrict__ cb1,
    const void* __restrict__ cW2, const void* __restrict__ cb2,
    float* __restrict__ ddx, float* __restrict__ t2g, float* __restrict__ Mkv,
    float (&xb)[4][DIN][2], float (&t1b)[4][H1][2], float (&t2b)[4][DM][2])
{
    const int w    = threadIdx.x >> 6;
    const int lane = threadIdx.x & 63;
    const int r0   = (blockIdx.x * 4 + w) * 2;   // rows r0, r0+1

    if (lane < 50) {
#pragma unroll
        for (int r = 0; r < 2; ++r) {
            const float2 xv = LD2<ISB>(text, (r0 + r) * 50 + lane);
            xb[w][2 * lane][r]     = xv.x;
            xb[w][2 * lane + 1][r] = xv.y;
        }
    }
    // wave-private LDS: no barrier anywhere in this kernel

    // ---- GEMM1 (100 -> 128): lane covers cols 2*lane, 2*lane+1 ----
    const float2 b1v = LD2<ISB>(tb1, lane);
    float ax0 = b1v.x, ay0 = b1v.y, ax1 = b1v.x, ay1 = b1v.y;
#pragma unroll 5
    for (int k = 0; k < DIN; ++k) {
        const float2 wv = LD2<ISB>(tW1, k * 64 + lane);
        const float2 xv = *(const float2*)&xb[w][k][0];
        ax0 += xv.x * wv.x; ay0 += xv.x * wv.y;
        ax1 += xv.y * wv.x; ay1 += xv.y * wv.y;
    }
    {   // LN(128)+LReLU, both rows via one quad-chain reduce
        float4 red = waveReduceSum4(make_float4(
            ax0 + ay0, ax0 * ax0 + ay0 * ay0,
            ax1 + ay1, ax1 * ax1 + ay1 * ay1));
        const float m0 = red.x * (1.f / 128.f);
        const float rs0 = rsqrtf(red.y * (1.f / 128.f) - m0 * m0 + 1e-5f);
        const float m1 = red.z * (1.f / 128.f);
        const float rs1 = rsqrtf(red.w * (1.f / 128.f) - m1 * m1 + 1e-5f);
        const float2 g = LD2<ISB>(tg1, lane), be = LD2<ISB>(tbe1, lane);
        t1b[w][2 * lane][0]     = lrelu((ax0 - m0) * rs0 * g.x + be.x);
        t1b[w][2 * lane + 1][0] = lrelu((ay0 - m0) * rs0 * g.y + be.y);
        t1b[w][2 * lane][1]     = lrelu((ax1 - m1) * rs1 * g.x + be.x);
        t1b[w][2 * lane + 1][1] = lrelu((ay1 - m1) * rs1 * g.y + be.y);
    }

    // ---- GEMM2 (128 -> 100): lanes 0..49 cover cols 2li, 2li+1 ----
    const bool act = lane < 50;
    const int  li  = act ? lane : 0;
    const float2 b2v = LD2<ISB>(tb2, li);
    float cx0 = b2v.x, cy0 = b2v.y, cx1 = b2v.x, cy1 = b2v.y;
#pragma unroll 8
    for (int k = 0; k < H1; ++k) {
        const float2 wv = LD2<ISB>(tW2, k * 50 + li);
        const float2 tv = *(const float2*)&t1b[w][k][0];
        cx0 += tv.x * wv.x; cy0 += tv.x * wv.y;
        cx1 += tv.y * wv.x; cy1 += tv.y * wv.y;
    }
    float u0x, u0y, u1x, u1y;   // t2 values for own cols
    {   // LN(100)+LReLU
        float4 red = waveReduceSum4(act ? make_float4(
            cx0 + cy0, cx0 * cx0 + cy0 * cy0,
            cx1 + cy1, cx1 * cx1 + cy1 * cy1) : make_float4(0.f, 0.f, 0.f, 0.f));
        const float m0 = red.x * 0.01f;
        const float rs0 = rsqrtf(red.y * 0.01f - m0 * m0 + 1e-5f);
        const float m1 = red.z * 0.01f;
        const float rs1 = rsqrtf(red.w * 0.01f - m1 * m1 + 1e-5f);
        const float2 g = LD2<ISB>(tg2, li), be = LD2<ISB>(tbe2, li);
        u0x = lrelu((cx0 - m0) * rs0 * g.x + be.x);
        u0y = lrelu((cy0 - m0) * rs0 * g.y + be.y);
        u1x = lrelu((cx1 - m1) * rs1 * g.x + be.x);
        u1y = lrelu((cy1 - m1) * rs1 * g.y + be.y);
        if (act) {
            t2b[w][2 * lane][0] = u0x; t2b[w][2 * lane + 1][0] = u0y;
            t2b[w][2 * lane][1] = u1x; t2b[w][2 * lane + 1][1] = u1y;
            *(float2*)(t2g + (r0)     * DM + 2 * lane) = make_float2(u0x, u0y);
            *(float2*)(t2g + (r0 + 1) * DM + 2 * lane) = make_float2(u1x, u1y);
        }
    }

    // ---- delta (100 cols) over k<100 ----
    const float2 sbv = LD2<ISB>(sb1, li);
    float dx0 = sbv.x, dy0 = sbv.y, dx1 = sbv.x, dy1 = sbv.y;
#pragma unroll 5
    for (int k = 0; k < DM; ++k) {
        const float2 wv = LD2<ISB>(sW1, k * 50 + li);
        const float2 tv = *(const float2*)&t2b[w][k][0];
        dx0 += tv.x * wv.x; dy0 += tv.x * wv.y;
        dx1 += tv.y * wv.x; dy1 += tv.y * wv.y;
    }
    if (act) {
        float de0 = softplusf(dx0), de1 = softplusf(dy0);
        float4 o;
        o.x = de0; o.y = de0 * u0x; o.z = de1; o.w = de1 * u0y;
        *(float4*)(ddx + (r0) * (2 * DM) + 4 * lane) = o;
        de0 = softplusf(dx1); de1 = softplusf(dy1);
        o.x = de0; o.y = de0 * u1x; o.z = de1; o.w = de1 * u1y;
        *(float4*)(ddx + (r0 + 1) * (2 * DM) + 4 * lane) = o;
    }

    // ---- side duty: collapsed head matrix M = cW1@cW2, k = cb1@cW2+cb2 ----
    if (blockIdx.x == 0 && w == 0) {
#pragma unroll
        for (int t = lane; t < 200; t += 64) {
            const int d = t >> 1, j = t & 1;
            float m = 0.f;
            for (int i = 0; i < 50; ++i)
                m += LD<ISB>(cW1, d * 50 + i) * LD<ISB>(cW2, 2 * i + j);
            Mkv[t] = m;
        }
        if (lane < 2) {
            float kv = LD<ISB>(cb2, lane);
            for (int i = 0; i < 50; ++i)
                kv += LD<ISB>(cb1, i) * LD<ISB>(cW2, 2 * i + lane);
            Mkv[200 + lane] = kv;
        }
    }
}

__global__ __launch_bounds__(256) void k_A(
    const void* text,
    const void* tW1, const void* tb1, const void* tg1, const void* tbe1,
    const void* tW2, const void* tb2, const void* tg2, const void* tbe2,
    const void* sW1, const void* sb1,
    const void* cW1, const void* cb1, const void* cW2, const void* cb2,
    float* ddx, float* t2g, float* Mkv, const unsigned short* probe)
{
    __shared__ __align__(16) float xb[4][DIN][2];
    __shared__ __align__(16) float t1b[4][H1][2];
    __shared__ __align__(16) float t2b[4][DM][2];
    if (detect_bf16(probe))
        a_impl<true >(text, tW1, tb1, tg1, tbe1, tW2, tb2, tg2, tbe2,
                      sW1, sb1, cW1, cb1, cW2, cb2, ddx, t2g, Mkv, xb, t1b, t2b);
    else
        a_impl<false>(text, tW1, tb1, tg1, tbe1, tW2, tb2, tg2, tbe2,
                      sW1, sb1, cW1, cb1, cW2, cb2, ddx, t2g, Mkv, xb, t1b, t2b);
}

// ---------------------------------------------------------------------------
// k_B: BC GEMM. 2 rows/wave, all 600 cols (150 pairs: cc<3, p=lane+64cc<150).
// Per k: 1 LDS b64 broadcast + 6 float2 weight loads -> 24 FMAs.
// ---------------------------------------------------------------------------
template<bool ISB>
__device__ __forceinline__ void b_impl(
    const float* __restrict__ t2g,
    const void* __restrict__ sW2, const void* __restrict__ sb2,
    const void* __restrict__ sW3, const void* __restrict__ sb3,
    float* __restrict__ BC, float (&sT)[4][DM][2])
{
    const int w    = threadIdx.x >> 6;
    const int lane = threadIdx.x & 63;
    const int r0   = (blockIdx.x * 4 + w) * 2;

    if (lane < 50) {
#pragma unroll
        for (int r = 0; r < 2; ++r) {
            const float2 tv = *(const float2*)(t2g + (r0 + r) * DM + 2 * lane);
            sT[w][2 * lane][r]     = tv.x;
            sT[w][2 * lane + 1][r] = tv.y;
        }
    }
    // wave-private: no barrier

    int pc[3]; bool pv[3];
    float2 aB[3][2], aC[3][2];
#pragma unroll
    for (int cc = 0; cc < 3; ++cc) {
        const int p = lane + 64 * cc;
        pv[cc] = p < 150;
        pc[cc] = pv[cc] ? p : 0;
        const float2 bb = LD2<ISB>(sb2, pc[cc]);
        const float2 cb = LD2<ISB>(sb3, pc[cc]);
        aB[cc][0] = bb; aB[cc][1] = bb;
        aC[cc][0] = cb; aC[cc][1] = cb;
    }
#pragma unroll 4
    for (int k = 0; k < DM; ++k) {
        const float2 tv = *(const float2*)&sT[w][k][0];
#pragma unroll
        for (int cc = 0; cc < 3; ++cc) {
            const float2 bw = LD2<ISB>(sW2, k * 150 + pc[cc]);
            const float2 cw = LD2<ISB>(sW3, k * 150 + pc[cc]);
            aB[cc][0].x += tv.x * bw.x; aB[cc][0].y += tv.x * bw.y;
            aB[cc][1].x += tv.y * bw.x; aB[cc][1].y += tv.y * bw.y;
            aC[cc][0].x += tv.x * cw.x; aC[cc][0].y += tv.x * cw.y;
            aC[cc][1].x += tv.y * cw.x; aC[cc][1].y += tv.y * cw.y;
        }
    }
#pragma unroll
    for (int cc = 0; cc < 3; ++cc) {
        if (pv[cc]) {
#pragma unroll
            for (int r = 0; r < 2; ++r) {
                float4 o;   // {B_2p, C_2p, B_2p+1, C_2p+1}
                o.x = aB[cc][r].x; o.y = aC[cc][r].x;
                o.z = aB[cc][r].y; o.w = aC[cc][r].y;
                *(float4*)(BC + (r0 + r) * (2 * NS) + 4 * pc[cc]) = o;
            }
        }
    }
}

__global__ __launch_bounds__(256) void k_B(
    const float* t2g, const void* sW2, const void* sb2,
    const void* sW3, const void* sb3, float* BC, const unsigned short* probe)
{
    __shared__ __align__(16) float sT[4][DM][2];
    if (detect_bf16(probe)) b_impl<true >(t2g, sW2, sb2, sW3, sb3, BC, sT);
    else                    b_impl<false>(t2g, sW2, sb2, sW3, sb3, BC, sT);
}

// ---------------------------------------------------------------------------
// k_scan: S6 scan with chunked parallel reduction (R7, unchanged).
// ---------------------------------------------------------------------------
template<bool ISB>
__device__ __forceinline__ void scan_impl(
    const float* __restrict__ ddx, const float* __restrict__ BC,
    const void* __restrict__ sA, float* __restrict__ y,
    float (&sacc)[4][16][2][68])
{
    const int w    = threadIdx.x >> 6;
    const int lane = threadIdx.x & 63;
    const int wid  = blockIdx.x * 4 + w;      // 0..3199
    const int b    = wid / 50;
    const int dp   = wid % 50;
    const int d0   = 2 * dp, d1 = d0 + 1;

    int nc[5]; bool nv[5];
    float A0[5], A1[5], h0[5], h1[5];
#pragma unroll
    for (int c = 0; c < 5; ++c) {
        const int n = lane + 64 * c;
        nv[c] = n < NS;
        nc[c] = nv[c] ? n : 0;
        A0[c] = nv[c] ? LD<ISB>(sA, d0 * NS + nc[c]) : 0.f;
        A1[c] = nv[c] ? LD<ISB>(sA, d1 * NS + nc[c]) : 0.f;
        h0[c] = 0.f; h1[c] = 0.f;
    }

    const float* ddp = ddx + (b * SEQ) * (2 * DM) + 4 * dp;
    const float* BCp = BC  + (b * SEQ) * (2 * NS);
    float*       yp  = y   + (b * SEQ) * DM + d0;

    float4 pdd[3];
    float2 pbc[3][5];
#pragma unroll
    for (int j = 0; j < 3; ++j) {
        pdd[j] = *(const float4*)(ddp + j * (2 * DM));
#pragma unroll
        for (int c = 0; c < 5; ++c)
            pbc[j][c] = nv[c] ? *(const float2*)(BCp + j * (2 * NS) + 2 * nc[c])
                              : make_float2(0.f, 0.f);
    }

    const int pr = lane >> 1;
    const int hh = lane & 1;
    const int sa = pr & 15;
    const int aa = pr >> 4;

#pragma unroll 3
    for (int l = 0; l < SEQ; ++l) {
        const int bi = l % 3;
        const float4 dd = pdd[bi];
        float2 bc[5];
#pragma unroll
        for (int c = 0; c < 5; ++c) bc[c] = pbc[bi][c];
        if (l + 3 < SEQ) {
            pdd[bi] = *(const float4*)(ddp + (l + 3) * (2 * DM));
#pragma unroll
            for (int c = 0; c < 5; ++c)
                pbc[bi][c] = nv[c] ? *(const float2*)(BCp + (l + 3) * (2 * NS) + 2 * nc[c])
                                   : make_float2(0.f, 0.f);
        }

        float a0 = 0.f, a1 = 0.f;
#pragma unroll
        for (int c = 0; c < 5; ++c) {
            h0[c] = __expf(dd.x * A0[c]) * h0[c] + dd.y * bc[c].x;
            a0 += bc[c].y * h0[c];
            h1[c] = __expf(dd.z * A1[c]) * h1[c] + dd.w * bc[c].x;
            a1 += bc[c].y * h1[c];
        }
        const int s = l & 15;
        sacc[w][s][0][lane] = a0;
        sacc[w][s][1][lane] = a1;

        if (s == 15 || l == SEQ - 1) {
            const int l0 = l & ~15;
            const int cs = l - l0 + 1;
            float sum = 0.f;
            if (sa < cs) {
                const float* rowp = &sacc[w][sa][aa][hh * 32];
#pragma unroll
                for (int i = 0; i < 8; ++i) {
                    const float4 v = *(const float4*)(rowp + 4 * i);
                    sum += v.x + v.y + v.z + v.w;
                }
            }
            sum += __shfl_xor(sum, 1, 64);
            if (hh == 0 && sa < cs) yp[(l0 + sa) * DM + aa] = sum;
        }
    }
}

__global__ __launch_bounds__(256) void k_scan(
    const float* ddx, const float* BC, const void* sA, float* y,
    const unsigned short* probe)
{
    __shared__ __align__(16) float sacc[4][16][2][68];
    if (detect_bf16(probe)) scan_impl<true >(ddx, BC, sA, y, sacc);
    else                    scan_impl<false>(ddx, BC, sA, y, sacc);
}

// ---------------------------------------------------------------------------
// k_head: out[row] = y[row] @ M + k. Thread per row.
// ---------------------------------------------------------------------------
template<bool ISB>
__device__ __forceinline__ void head_impl(
    const float* __restrict__ y, const float* __restrict__ Mkv,
    void* __restrict__ outp)
{
    const int row = blockIdx.x * 256 + threadIdx.x;
    if (row >= ROWS) return;
    float a0 = Mkv[200], a1 = Mkv[201];
    const float* yr = y + row * DM;
#pragma unroll 4
    for (int k = 0; k < DM; ++k) {
        const float v = yr[k];
        const float2 m = *(const float2*)(Mkv + 2 * k);
        a0 += v * m.x;
        a1 += v * m.y;
    }
    if (ISB) {
        ((bf16*)outp)[row * 2 + 0] = __float2bfloat16(a0);
        ((bf16*)outp)[row * 2 + 1] = __float2bfloat16(a1);
    } else {
        *(float2*)((float*)outp + row * 2) = make_float2(a0, a1);
    }
}

__global__ __launch_bounds__(256) void k_head(
    const float* y, const float* Mkv, void* outp, const unsigned short* probe)
{
    if (detect_bf16(probe)) head_impl<true >(y, Mkv, outp);
    else                    head_impl<false>(y, Mkv, outp);
}

// ---------------------------------------------------------------------------
extern "C" void kernel_launch(void* const* d_in, const int* in_sizes, int n_in,
                              void* d_out, int out_size, void* d_ws, size_t ws_size,
                              hipStream_t stream)
{
    const void* text = d_in[0];
    const void* tW1  = d_in[3];
    const void* tb1  = d_in[4];
    const void* tg1  = d_in[5];
    const void* tbe1 = d_in[6];
    const void* tW2  = d_in[7];
    const void* tb2  = d_in[8];
    const void* tg2  = d_in[9];
    const void* tbe2 = d_in[10];
    const void* sW1  = d_in[11];
    const void* sb1  = d_in[12];
    const void* sW2  = d_in[13];
    const void* sb2  = d_in[14];
    const void* sW3  = d_in[15];
    const void* sb3  = d_in[16];
    const void* sA   = d_in[17];
    const void* cW1  = d_in[34];
    const void* cb1  = d_in[35];
    const void* cW2  = d_in[36];
    const void* cb2  = d_in[37];
    const unsigned short* probe = (const unsigned short*)d_in[3];

    float* ws  = (float*)d_ws;
    float* ddx = ws;                          // ROWS * 200
    float* BCv = ddx + ROWS * 2 * DM;         // ROWS * 600
    float* yv  = BCv + ROWS * 2 * NS;         // ROWS * 100 (t2g then y — aliased)
    float* Mkv = yv + ROWS * DM;              // 202        (~14.5 MB total)
    float* t2g = yv;                          // alias: t2 dead before scan writes y

    k_A<<<ROWS / 8, 256, 0, stream>>>(
        text, tW1, tb1, tg1, tbe1, tW2, tb2, tg2, tbe2,
        sW1, sb1, cW1, cb1, cW2, cb2, ddx, t2g, Mkv, probe);

    k_B<<<ROWS / 8, 256, 0, stream>>>(t2g, sW2, sb2, sW3, sb3, BCv, probe);

    k_scan<<<3200 / 4, 256, 0, stream>>>(ddx, BCv, sA, yv, probe);

    k_head<<<(ROWS + 255) / 256, 256, 0, stream>>>(yv, Mkv, d_out, probe);
}

// Round 9
// 244.709 us; speedup vs baseline: 1.2724x; 1.2724x over previous
//
#include <hip/hip_runtime.h>
#include <hip/hip_bf16.h>

// Simple_6270652252303. Inputs float32 (detector-verified; bf16 path kept as
// insurance). Text branch only feeds output.
//   k_A:    text -> LN -> LN -> t2(global); + collapsed head matrix Mkv.
//           2 rows/wave, grid 504, ring-prefetch (10/8) on weight streams.
//   k_B:    {delta->ddx} + {B,C}->BC GEMM. 8 rows/block, 192 thr, thread =
//           4 cols x 8 rows, t2 in LDS [k][8], ring-prefetch 4 on float4 W.
//   k_scan: S6 scan, chunked parallel reduction (R7) -> y.
//   k_head: out[row] = y[row] @ Mkv + k (thread per row).

typedef __hip_bfloat16 bf16;

#define BATCH 64
#define SEQ   63
#define ROWS  (BATCH * SEQ)   // 4032
#define DIN   100
#define H1    128
#define DM    100
#define NS    300

__device__ __forceinline__ float2 up2(unsigned u) {
    float2 r;
    r.x = __uint_as_float(u << 16);
    r.y = __uint_as_float(u & 0xffff0000u);
    return r;
}
template<bool ISB>
__device__ __forceinline__ float LD(const void* p, int i) {
    if (ISB) return __bfloat162float(((const bf16*)p)[i]);
    else     return ((const float*)p)[i];
}
template<bool ISB>
__device__ __forceinline__ float2 LD2(const void* p, int i) {   // elems 2i,2i+1
    if (ISB) return up2(((const unsigned*)p)[i]);
    else     return ((const float2*)p)[i];
}
template<bool ISB>
__device__ __forceinline__ float4 LD4(const void* p, int i) {   // elems 4i..4i+3
    if (ISB) {
        const uint2 u = ((const uint2*)p)[i];
        float4 r;
        r.x = __uint_as_float(u.x << 16);
        r.y = __uint_as_float(u.x & 0xffff0000u);
        r.z = __uint_as_float(u.y << 16);
        r.w = __uint_as_float(u.y & 0xffff0000u);
        return r;
    } else return ((const float4*)p)[i];
}
// four independent reduction chains interleaved (latencies overlap)
__device__ __forceinline__ float4 waveReduceSum4(float4 v) {
#pragma unroll
    for (int off = 32; off > 0; off >>= 1) {
        const float a = __shfl_xor(v.x, off, 64);
        const float b = __shfl_xor(v.y, off, 64);
        const float c = __shfl_xor(v.z, off, 64);
        const float d = __shfl_xor(v.w, off, 64);
        v.x += a; v.y += b; v.z += c; v.w += d;
    }
    return v;
}
__device__ __forceinline__ float lrelu(float x) { return x >= 0.f ? x : 0.01f * x; }
__device__ __forceinline__ float softplusf(float x) {
    return (x > 20.f) ? x : log1pf(__expf(x));
}

// bf16-vs-f32 storage detector (wave-uniform ballot; no LDS, no barrier).
__device__ __forceinline__ bool detect_bf16(const unsigned short* __restrict__ probe) {
    const int l = threadIdx.x & 63;
    const unsigned u0 = probe[l * 2];
    const unsigned u1 = probe[l * 2 + 1];
    const float v0 = fabsf(__uint_as_float(u0 << 16));
    const float v1 = fabsf(__uint_as_float(u1 << 16));
    const bool big = !(v0 < 1000.f) || !(v1 < 1000.f);
    const bool zero_even = (u0 == 0u);
    const unsigned long long mb = __ballot(big);
    const unsigned long long mz = __ballot(zero_even);
    return (mb == 0ULL) && (__popcll(mz) < 32);
}

// ---------------------------------------------------------------------------
// k_A: GEMM1 -> LN -> GEMM2 -> LN -> t2g. 2 rows/wave, 4 waves/block, grid 504.
// Weight streams use explicit register prefetch rings (depth 10 / 8).
// ---------------------------------------------------------------------------
template<bool ISB>
__device__ __forceinline__ void a_impl(
    const void* __restrict__ text,
    const void* __restrict__ tW1, const void* __restrict__ tb1,
    const void* __restrict__ tg1, const void* __restrict__ tbe1,
    const void* __restrict__ tW2, const void* __restrict__ tb2,
    const void* __restrict__ tg2, const void* __restrict__ tbe2,
    const void* __restrict__ cW1, const void* __restrict__ cb1,
    const void* __restrict__ cW2, const void* __restrict__ cb2,
    float* __restrict__ t2g, float* __restrict__ Mkv,
    float (&xb)[4][DIN][2], float (&t1b)[4][H1][2])
{
    const int w    = threadIdx.x >> 6;
    const int lane = threadIdx.x & 63;
    const int r0   = blockIdx.x * 8 + w * 2;   // rows r0, r0+1

    if (lane < 50) {
#pragma unroll
        for (int r = 0; r < 2; ++r) {
            const float2 xv = LD2<ISB>(text, (r0 + r) * 50 + lane);
            xb[w][2 * lane][r]     = xv.x;
            xb[w][2 * lane + 1][r] = xv.y;
        }
    }
    // wave-private LDS: no barrier anywhere

    // ---- GEMM1 (100 -> 128), ring prefetch depth 10 ----
    const float2 b1v = LD2<ISB>(tb1, lane);
    float ax0 = b1v.x, ay0 = b1v.y, ax1 = b1v.x, ay1 = b1v.y;
    {
        float2 ring[10];
#pragma unroll
        for (int j = 0; j < 10; ++j) ring[j] = LD2<ISB>(tW1, j * 64 + lane);
        for (int kk = 0; kk < DIN; kk += 10) {
#pragma unroll
            for (int j = 0; j < 10; ++j) {
                const int k = kk + j;
                const float2 wv = ring[j];
                if (k + 10 < DIN) ring[j] = LD2<ISB>(tW1, (k + 10) * 64 + lane);
                const float2 xv = *(const float2*)&xb[w][k][0];
                ax0 += xv.x * wv.x; ay0 += xv.x * wv.y;
                ax1 += xv.y * wv.x; ay1 += xv.y * wv.y;
            }
        }
    }
    {   // LN(128)+LReLU, both rows via one quad-chain reduce
        float4 red = waveReduceSum4(make_float4(
            ax0 + ay0, ax0 * ax0 + ay0 * ay0,
            ax1 + ay1, ax1 * ax1 + ay1 * ay1));
        const float m0 = red.x * (1.f / 128.f);
        const float rs0 = rsqrtf(red.y * (1.f / 128.f) - m0 * m0 + 1e-5f);
        const float m1 = red.z * (1.f / 128.f);
        const float rs1 = rsqrtf(red.w * (1.f / 128.f) - m1 * m1 + 1e-5f);
        const float2 g = LD2<ISB>(tg1, lane), be = LD2<ISB>(tbe1, lane);
        float2 v;
        v.x = lrelu((ax0 - m0) * rs0 * g.x + be.x);
        v.y = lrelu((ax1 - m1) * rs1 * g.x + be.x);
        *(float2*)&t1b[w][2 * lane][0] = v;
        v.x = lrelu((ay0 - m0) * rs0 * g.y + be.y);
        v.y = lrelu((ay1 - m1) * rs1 * g.y + be.y);
        *(float2*)&t1b[w][2 * lane + 1][0] = v;
    }

    // ---- GEMM2 (128 -> 100), ring prefetch depth 8 ----
    const bool act = lane < 50;
    const int  li  = act ? lane : 0;
    const float2 b2v = LD2<ISB>(tb2, li);
    float cx0 = b2v.x, cy0 = b2v.y, cx1 = b2v.x, cy1 = b2v.y;
    {
        float2 ring[8];
#pragma unroll
        for (int j = 0; j < 8; ++j) ring[j] = LD2<ISB>(tW2, j * 50 + li);
        for (int kk = 0; kk < H1; kk += 8) {
#pragma unroll
            for (int j = 0; j < 8; ++j) {
                const int k = kk + j;
                const float2 wv = ring[j];
                if (k + 8 < H1) ring[j] = LD2<ISB>(tW2, (k + 8) * 50 + li);
                const float2 tv = *(const float2*)&t1b[w][k][0];
                cx0 += tv.x * wv.x; cy0 += tv.x * wv.y;
                cx1 += tv.y * wv.x; cy1 += tv.y * wv.y;
            }
        }
    }
    {   // LN(100)+LReLU -> t2g
        float4 red = waveReduceSum4(act ? make_float4(
            cx0 + cy0, cx0 * cx0 + cy0 * cy0,
            cx1 + cy1, cx1 * cx1 + cy1 * cy1) : make_float4(0.f, 0.f, 0.f, 0.f));
        const float m0 = red.x * 0.01f;
        const float rs0 = rsqrtf(red.y * 0.01f - m0 * m0 + 1e-5f);
        const float m1 = red.z * 0.01f;
        const float rs1 = rsqrtf(red.w * 0.01f - m1 * m1 + 1e-5f);
        if (act) {
            const float2 g = LD2<ISB>(tg2, lane), be = LD2<ISB>(tbe2, lane);
            float2 o0, o1;
            o0.x = lrelu((cx0 - m0) * rs0 * g.x + be.x);
            o0.y = lrelu((cy0 - m0) * rs0 * g.y + be.y);
            o1.x = lrelu((cx1 - m1) * rs1 * g.x + be.x);
            o1.y = lrelu((cy1 - m1) * rs1 * g.y + be.y);
            *(float2*)(t2g + (r0)     * DM + 2 * lane) = o0;
            *(float2*)(t2g + (r0 + 1) * DM + 2 * lane) = o1;
        }
    }

    // ---- side duty: collapsed head M = cW1@cW2, k = cb1@cW2+cb2 ----
    if (blockIdx.x == 0 && w == 0) {
#pragma unroll
        for (int t = lane; t < 200; t += 64) {
            const int d = t >> 1, j = t & 1;
            float m = 0.f;
            for (int i = 0; i < 50; ++i)
                m += LD<ISB>(cW1, d * 50 + i) * LD<ISB>(cW2, 2 * i + j);
            Mkv[t] = m;
        }
        if (lane < 2) {
            float kv = LD<ISB>(cb2, lane);
            for (int i = 0; i < 50; ++i)
                kv += LD<ISB>(cb1, i) * LD<ISB>(cW2, 2 * i + lane);
            Mkv[200 + lane] = kv;
        }
    }
}

__global__ __launch_bounds__(256, 1) void k_A(
    const void* text,
    const void* tW1, const void* tb1, const void* tg1, const void* tbe1,
    const void* tW2, const void* tb2, const void* tg2, const void* tbe2,
    const void* cW1, const void* cb1, const void* cW2, const void* cb2,
    float* t2g, float* Mkv, const unsigned short* probe)
{
    __shared__ __align__(16) float xb[4][DIN][2];
    __shared__ __align__(16) float t1b[4][H1][2];
    if (detect_bf16(probe))
        a_impl<true >(text, tW1, tb1, tg1, tbe1, tW2, tb2, tg2, tbe2,
                      cW1, cb1, cW2, cb2, t2g, Mkv, xb, t1b);
    else
        a_impl<false>(text, tW1, tb1, tg1, tbe1, tW2, tb2, tg2, tbe2,
                      cW1, cb1, cW2, cb2, t2g, Mkv, xb, t1b);
}

// ---------------------------------------------------------------------------
// k_B: delta/B/C GEMM. Block = 192 thr, 8 rows. Thread t: 4 cols x 8 rows.
//   t<25: delta cols 4t (sW1) -> ddx {de,de*x};  25<=t<100: B (sW2);
//   100<=t<175: C (sW3); t>=175 idle. Ring-prefetch depth 4 on float4 weights.
// ---------------------------------------------------------------------------
template<bool ISB>
__device__ __forceinline__ void b_impl(
    const float* __restrict__ t2g,
    const void* __restrict__ sW1, const void* __restrict__ sb1,
    const void* __restrict__ sW2, const void* __restrict__ sb2,
    const void* __restrict__ sW3, const void* __restrict__ sb3,
    float* __restrict__ ddx, float* __restrict__ BC,
    float (&sT)[DM][8])
{
    const int t  = threadIdx.x;
    const int r0 = blockIdx.x * 8;

    // stage t2 rows transposed: sT[k][r]
    if (t < DM) {
#pragma unroll
        for (int r = 0; r < 8; ++r)
            sT[t][r] = t2g[(r0 + r) * DM + t];
    }
    __syncthreads();

    const bool isD = t < 25;
    const bool isB = !isD && t < 100;
    const bool valid = t < 175;
    const int colbase = isD ? 4 * t : (isB ? 4 * (t - 25) : (valid ? 4 * (t - 100) : 0));
    const void* Wp   = isD ? sW1 : (isB ? sW2 : sW3);
    const void* bias = isD ? sb1 : (isB ? sb2 : sb3);
    const int rs4 = (isD ? DM : NS) >> 2;        // row stride in float4 units
    const int cb4 = colbase >> 2;

    float4 acc[8];
    {
        const float4 bv = LD4<ISB>(bias, cb4);
#pragma unroll
        for (int r = 0; r < 8; ++r) acc[r] = bv;
    }

    float4 ring[4];
#pragma unroll
    for (int j = 0; j < 4; ++j) ring[j] = LD4<ISB>(Wp, j * rs4 + cb4);
    for (int kk = 0; kk < DM; kk += 4) {
#pragma unroll
        for (int j = 0; j < 4; ++j) {
            const int k = kk + j;
            const float4 wv = ring[j];
            if (k + 4 < DM) ring[j] = LD4<ISB>(Wp, (k + 4) * rs4 + cb4);
            const float4 lo = *(const float4*)&sT[k][0];   // rows 0..3 (broadcast)
            const float4 hi = *(const float4*)&sT[k][4];   // rows 4..7
            acc[0].x += lo.x * wv.x; acc[0].y += lo.x * wv.y; acc[0].z += lo.x * wv.z; acc[0].w += lo.x * wv.w;
            acc[1].x += lo.y * wv.x; acc[1].y += lo.y * wv.y; acc[1].z += lo.y * wv.z; acc[1].w += lo.y * wv.w;
            acc[2].x += lo.z * wv.x; acc[2].y += lo.z * wv.y; acc[2].z += lo.z * wv.z; acc[2].w += lo.z * wv.w;
            acc[3].x += lo.w * wv.x; acc[3].y += lo.w * wv.y; acc[3].z += lo.w * wv.z; acc[3].w += lo.w * wv.w;
            acc[4].x += hi.x * wv.x; acc[4].y += hi.x * wv.y; acc[4].z += hi.x * wv.z; acc[4].w += hi.x * wv.w;
            acc[5].x += hi.y * wv.x; acc[5].y += hi.y * wv.y; acc[5].z += hi.y * wv.z; acc[5].w += hi.y * wv.w;
            acc[6].x += hi.z * wv.x; acc[6].y += hi.z * wv.y; acc[6].z += hi.z * wv.z; acc[6].w += hi.z * wv.w;
            acc[7].x += hi.w * wv.x; acc[7].y += hi.w * wv.y; acc[7].z += hi.w * wv.z; acc[7].w += hi.w * wv.w;
        }
    }

    if (valid) {
        if (isD) {
#pragma unroll
            for (int r = 0; r < 8; ++r) {
                const int row = r0 + r;
                const float de0 = softplusf(acc[r].x);
                const float de1 = softplusf(acc[r].y);
                const float de2 = softplusf(acc[r].z);
                const float de3 = softplusf(acc[r].w);
                float4 o;
                o.x = de0; o.y = de0 * sT[colbase + 0][r];
                o.z = de1; o.w = de1 * sT[colbase + 1][r];
                *(float4*)(ddx + row * (2 * DM) + 2 * colbase) = o;
                o.x = de2; o.y = de2 * sT[colbase + 2][r];
                o.z = de3; o.w = de3 * sT[colbase + 3][r];
                *(float4*)(ddx + row * (2 * DM) + 2 * colbase + 4) = o;
            }
        } else {
            const int off = isB ? 0 : 1;
#pragma unroll
            for (int r = 0; r < 8; ++r) {
                float* bp = BC + (r0 + r) * (2 * NS) + 2 * colbase + off;
                bp[0] = acc[r].x; bp[2] = acc[r].y;
                bp[4] = acc[r].z; bp[6] = acc[r].w;
            }
        }
    }
}

__global__ __launch_bounds__(192, 1) void k_B(
    const float* t2g,
    const void* sW1, const void* sb1, const void* sW2, const void* sb2,
    const void* sW3, const void* sb3,
    float* ddx, float* BC, const unsigned short* probe)
{
    __shared__ __align__(16) float sT[DM][8];
    if (detect_bf16(probe))
        b_impl<true >(t2g, sW1, sb1, sW2, sb2, sW3, sb3, ddx, BC, sT);
    else
        b_impl<false>(t2g, sW1, sb1, sW2, sb2, sW3, sb3, ddx, BC, sT);
}

// ---------------------------------------------------------------------------
// k_scan: S6 scan with chunked parallel reduction (R7, unchanged).
// ---------------------------------------------------------------------------
template<bool ISB>
__device__ __forceinline__ void scan_impl(
    const float* __restrict__ ddx, const float* __restrict__ BC,
    const void* __restrict__ sA, float* __restrict__ y,
    float (&sacc)[4][16][2][68])
{
    const int w    = threadIdx.x >> 6;
    const int lane = threadIdx.x & 63;
    const int wid  = blockIdx.x * 4 + w;      // 0..3199
    const int b    = wid / 50;
    const int dp   = wid % 50;
    const int d0   = 2 * dp, d1 = d0 + 1;

    int nc[5]; bool nv[5];
    float A0[5], A1[5], h0[5], h1[5];
#pragma unroll
    for (int c = 0; c < 5; ++c) {
        const int n = lane + 64 * c;
        nv[c] = n < NS;
        nc[c] = nv[c] ? n : 0;
        A0[c] = nv[c] ? LD<ISB>(sA, d0 * NS + nc[c]) : 0.f;
        A1[c] = nv[c] ? LD<ISB>(sA, d1 * NS + nc[c]) : 0.f;
        h0[c] = 0.f; h1[c] = 0.f;
    }

    const float* ddp = ddx + (b * SEQ) * (2 * DM) + 4 * dp;
    const float* BCp = BC  + (b * SEQ) * (2 * NS);
    float*       yp  = y   + (b * SEQ) * DM + d0;

    float4 pdd[3];
    float2 pbc[3][5];
#pragma unroll
    for (int j = 0; j < 3; ++j) {
        pdd[j] = *(const float4*)(ddp + j * (2 * DM));
#pragma unroll
        for (int c = 0; c < 5; ++c)
            pbc[j][c] = nv[c] ? *(const float2*)(BCp + j * (2 * NS) + 2 * nc[c])
                              : make_float2(0.f, 0.f);
    }

    const int pr = lane >> 1;
    const int hh = lane & 1;
    const int sa = pr & 15;
    const int aa = pr >> 4;

#pragma unroll 3
    for (int l = 0; l < SEQ; ++l) {
        const int bi = l % 3;
        const float4 dd = pdd[bi];
        float2 bc[5];
#pragma unroll
        for (int c = 0; c < 5; ++c) bc[c] = pbc[bi][c];
        if (l + 3 < SEQ) {
            pdd[bi] = *(const float4*)(ddp + (l + 3) * (2 * DM));
#pragma unroll
            for (int c = 0; c < 5; ++c)
                pbc[bi][c] = nv[c] ? *(const float2*)(BCp + (l + 3) * (2 * NS) + 2 * nc[c])
                                   : make_float2(0.f, 0.f);
        }

        float a0 = 0.f, a1 = 0.f;
#pragma unroll
        for (int c = 0; c < 5; ++c) {
            h0[c] = __expf(dd.x * A0[c]) * h0[c] + dd.y * bc[c].x;
            a0 += bc[c].y * h0[c];
            h1[c] = __expf(dd.z * A1[c]) * h1[c] + dd.w * bc[c].x;
            a1 += bc[c].y * h1[c];
        }
        const int s = l & 15;
        sacc[w][s][0][lane] = a0;
        sacc[w][s][1][lane] = a1;

        if (s == 15 || l == SEQ - 1) {
            const int l0 = l & ~15;
            const int cs = l - l0 + 1;
            float sum = 0.f;
            if (sa < cs) {
                const float* rowp = &sacc[w][sa][aa][hh * 32];
#pragma unroll
                for (int i = 0; i < 8; ++i) {
                    const float4 v = *(const float4*)(rowp + 4 * i);
                    sum += v.x + v.y + v.z + v.w;
                }
            }
            sum += __shfl_xor(sum, 1, 64);
            if (hh == 0 && sa < cs) yp[(l0 + sa) * DM + aa] = sum;
        }
    }
}

__global__ __launch_bounds__(256) void k_scan(
    const float* ddx, const float* BC, const void* sA, float* y,
    const unsigned short* probe)
{
    __shared__ __align__(16) float sacc[4][16][2][68];
    if (detect_bf16(probe)) scan_impl<true >(ddx, BC, sA, y, sacc);
    else                    scan_impl<false>(ddx, BC, sA, y, sacc);
}

// ---------------------------------------------------------------------------
// k_head: out[row] = y[row] @ M + k. Thread per row.
// ---------------------------------------------------------------------------
template<bool ISB>
__device__ __forceinline__ void head_impl(
    const float* __restrict__ y, const float* __restrict__ Mkv,
    void* __restrict__ outp)
{
    const int row = blockIdx.x * 256 + threadIdx.x;
    if (row >= ROWS) return;
    float a0 = Mkv[200], a1 = Mkv[201];
    const float* yr = y + row * DM;
#pragma unroll 4
    for (int k = 0; k < DM; ++k) {
        const float v = yr[k];
        const float2 m = *(const float2*)(Mkv + 2 * k);
        a0 += v * m.x;
        a1 += v * m.y;
    }
    if (ISB) {
        ((bf16*)outp)[row * 2 + 0] = __float2bfloat16(a0);
        ((bf16*)outp)[row * 2 + 1] = __float2bfloat16(a1);
    } else {
        *(float2*)((float*)outp + row * 2) = make_float2(a0, a1);
    }
}

__global__ __launch_bounds__(256) void k_head(
    const float* y, const float* Mkv, void* outp, const unsigned short* probe)
{
    if (detect_bf16(probe)) head_impl<true >(y, Mkv, outp);
    else                    head_impl<false>(y, Mkv, outp);
}

// ---------------------------------------------------------------------------
extern "C" void kernel_launch(void* const* d_in, const int* in_sizes, int n_in,
                              void* d_out, int out_size, void* d_ws, size_t ws_size,
                              hipStream_t stream)
{
    const void* text = d_in[0];
    const void* tW1  = d_in[3];
    const void* tb1  = d_in[4];
    const void* tg1  = d_in[5];
    const void* tbe1 = d_in[6];
    const void* tW2  = d_in[7];
    const void* tb2  = d_in[8];
    const void* tg2  = d_in[9];
    const void* tbe2 = d_in[10];
    const void* sW1  = d_in[11];
    const void* sb1  = d_in[12];
    const void* sW2  = d_in[13];
    const void* sb2  = d_in[14];
    const void* sW3  = d_in[15];
    const void* sb3  = d_in[16];
    const void* sA   = d_in[17];
    const void* cW1  = d_in[34];
    const void* cb1  = d_in[35];
    const void* cW2  = d_in[36];
    const void* cb2  = d_in[37];
    const unsigned short* probe = (const unsigned short*)d_in[3];

    float* ws  = (float*)d_ws;
    float* ddx = ws;                          // ROWS * 200
    float* BCv = ddx + ROWS * 2 * DM;         // ROWS * 600
    float* yv  = BCv + ROWS * 2 * NS;         // ROWS * 100 (t2g then y — aliased)
    float* Mkv = yv + ROWS * DM;              // 202
    float* t2g = yv;                          // alias: t2 dead before scan writes y

    k_A<<<ROWS / 8, 256, 0, stream>>>(
        text, tW1, tb1, tg1, tbe1, tW2, tb2, tg2, tbe2,
        cW1, cb1, cW2, cb2, t2g, Mkv, probe);

    k_B<<<ROWS / 8, 192, 0, stream>>>(
        t2g, sW1, sb1, sW2, sb2, sW3, sb3, ddx, BCv, probe);

    k_scan<<<3200 / 4, 256, 0, stream>>>(ddx, BCv, sA, yv, probe);

    k_head<<<(ROWS + 255) / 256, 256, 0, stream>>>(yv, Mkv, d_out, probe);
}